// Round 3
// baseline (266.838 us; speedup 1.0000x reference)
//
#include <hip/hip_runtime.h>
#include <hip/hip_bf16.h>
#include <stdint.h>

typedef __attribute__((ext_vector_type(8))) short short8;
typedef __bf16 bf16x8 __attribute__((ext_vector_type(8)));
typedef __attribute__((ext_vector_type(4))) float f32x4;

#define HID 128
#define NTILES 8   // 8 column tiles of 16 -> 128 hidden units
#define KSTEPS 4   // 4 K-steps of 32 -> K=128

// ws layout (float index): [0,8192) bfrag (short[16384]); [8192,8448) cw as float2
// pairs {c[j], w2[j]}; [8448] b2.  LDS copy: 2112 * int4 = 33792 B (floats [0,8448)).
#define WS_CW_F   8192
#define WS_B2_F   8448

#define GRID_BLOCKS 1024
#define TOTAL_WAVES (GRID_BLOCKS * 4)

// ---------------- prep: heads (out[0:39], fp32 exact) + pack teleport weights into ws
__global__ void prep_kernel(const float* __restrict__ node_hidden,
                            const float* __restrict__ h_glob,
                            const float* __restrict__ state,
                            const float* __restrict__ validity,
                            const float* __restrict__ W_hl1, const float* __restrict__ b_hl1,
                            const float* __restrict__ W_hl2, const float* __restrict__ b_hl2,
                            const float* __restrict__ W_in1, const float* __restrict__ b_in1,
                            const float* __restrict__ W_in2, const float* __restrict__ b_in2,
                            const float* __restrict__ W_ex1, const float* __restrict__ b_ex1,
                            const float* __restrict__ W_ex2, const float* __restrict__ b_ex2,
                            const float* __restrict__ W_tp1, const float* __restrict__ b_tp1,
                            const float* __restrict__ W_tp2, const float* __restrict__ b_tp2,
                            float* __restrict__ out, float* __restrict__ ws)
{
    __shared__ float feats[264];
    __shared__ float hidden[3 * 128];
    const int tid = threadIdx.x;

    for (int i = tid; i < 264; i += 256) {
        float v;
        if (i < 128)      v = node_hidden[i];       // feats = [cur, h_glob, state]
        else if (i < 256) v = h_glob[i - 128];
        else              v = state[i - 256];
        feats[i] = v;
    }
    __syncthreads();

    for (int hid = tid; hid < 384; hid += 256) {
        const int head = hid >> 7, j = hid & 127;
        const float* W1 = (head == 0) ? W_hl1 : (head == 1 ? W_in1 : W_ex1);
        const float* b1 = (head == 0) ? b_hl1 : (head == 1 ? b_in1 : b_ex1);
        float h = b1[j];
        for (int i = 0; i < 264; ++i) h += feats[i] * W1[i * 128 + j];
        hidden[hid] = h > 0.f ? h : 0.f;
    }
    __syncthreads();

    if (tid < 39) {
        int head, col, od;
        const float *W2, *b2;
        if (tid < 4)      { head = 0; col = tid;     W2 = W_hl2; b2 = b_hl2; od = 4;  }
        else if (tid < 9) { head = 1; col = tid - 4; W2 = W_in2; b2 = b_in2; od = 5;  }
        else              { head = 2; col = tid - 9; W2 = W_ex2; b2 = b_ex2; od = 30; }
        float o = b2[col];
        const float* h = &hidden[head * 128];
        for (int i = 0; i < 128; ++i) o += h[i] * W2[i * od + col];
        if (head == 2) o += logf(validity[col]);
        out[tid] = o;
    }

    // ---- pack B = W_tp1[128:256,:] as bf16 MFMA B-fragments into ws
    short* bfrag = (short*)ws;
    for (int idx = tid; idx < HID * HID; idx += 256) {
        const int k = idx >> 7, nn = idx & 127;
        const int t = nn >> 4, cc = nn & 15;
        const int s = k >> 5, rr = k & 31;
        const int g = rr >> 3, j = rr & 7;
        const int lane = cc + (g << 4);
        bfrag[(((t * KSTEPS + s) * 64 + lane) << 3) + j] =
            (short)__builtin_bit_cast(unsigned short, (__bf16)W_tp1[(128 + k) * HID + nn]);
    }
    // ---- constant layer-1 offset: c = b1 + h_glob @ W1[0:128] + state @ W1[256:264]
    for (int j = tid; j < HID; j += 256) {
        float c = b_tp1[j];
        for (int i = 0; i < 128; ++i) c += h_glob[i] * W_tp1[i * HID + j];
        for (int i = 0; i < 8;  ++i)  c += state[i] * W_tp1[(256 + i) * HID + j];
        ws[WS_CW_F + 2 * j]     = c;
        ws[WS_CW_F + 2 * j + 1] = W_tp2[j];
    }
    if (tid == 0) ws[WS_B2_F] = b_tp2[0];
}

// ---------------- teleport: per-node FFN, bf16 MFMA, fused epilogue -> out[39 + i]
__launch_bounds__(256, 4)
__global__ void teleport_kernel(const float* __restrict__ node_hidden, // n x 128
                                const float* __restrict__ ws,          // packed weights
                                float* __restrict__ out,               // pre-offset (+39)
                                int n)
{
    __shared__ __align__(16) unsigned char smem[33792]; // bfrag 32KB | cw 1KB
    const int tid = threadIdx.x;

    // coalesced ws -> LDS copy (2112 int4)
    {
        const int4* wsv = (const int4*)ws;
        int4* sv = (int4*)smem;
        #pragma unroll
        for (int i = 0; i < 9; ++i) {
            const int idx = tid + i * 256;
            if (idx < 2112) sv[idx] = wsv[idx];
        }
    }
    const float bias2 = ws[WS_B2_F];
    __syncthreads();

    const short*  bfrag  = (const short*)smem;
    const float2* cw_all = (const float2*)(smem + 32768);

    const int lane = tid & 63;
    const int wave = tid >> 6;
    const int m = lane & 15;   // A row within tile / C col (hidden unit)
    const int g = lane >> 4;   // k-group / C row-group

    const int nChunks = (n + 15) >> 4;
    const int gw = (blockIdx.x << 2) | wave;
    const int c0 = (int)(((long long)gw * nChunks) / TOTAL_WAVES);
    const int c1 = (int)(((long long)(gw + 1) * nChunks) / TOTAL_WAVES);
    if (c0 >= c1) return;

    // per-lane A source: row = chunk*16 + m, cols [g*8, g*8+8) of each 32-K step
#define LOAD_CHUNK(dst, cc_)                                                    \
    {                                                                           \
        const int row_ = min((cc_) * 16 + m, n - 1);                            \
        const float4* Ar_ = (const float4*)(node_hidden + (size_t)row_ * HID);  \
        _Pragma("unroll")                                                       \
        for (int s_ = 0; s_ < KSTEPS; ++s_) {                                   \
            dst[s_ * 2]     = Ar_[s_ * 8 + g * 2];                              \
            dst[s_ * 2 + 1] = Ar_[s_ * 8 + g * 2 + 1];                          \
        }                                                                       \
    }

    float4 cur[8], nxt[8];
    LOAD_CHUNK(cur, c0)

    for (int c = c0; c < c1; ++c) {
        const bool hasNext = (c + 1 < c1);
        if (hasNext) LOAD_CHUNK(nxt, c + 1)

        f32x4 acc[NTILES];
        #pragma unroll
        for (int t = 0; t < NTILES; ++t) acc[t] = (f32x4){0.f, 0.f, 0.f, 0.f};

        #pragma unroll
        for (int s = 0; s < KSTEPS; ++s) {
            const float4 fa = cur[s * 2];
            const float4 fb = cur[s * 2 + 1];
            bf16x8 a;
            a[0] = (__bf16)fa.x; a[1] = (__bf16)fa.y; a[2] = (__bf16)fa.z; a[3] = (__bf16)fa.w;
            a[4] = (__bf16)fb.x; a[5] = (__bf16)fb.y; a[6] = (__bf16)fb.z; a[7] = (__bf16)fb.w;
            #pragma unroll
            for (int t = 0; t < NTILES; ++t) {
                const short8 bs = *(const short8*)&bfrag[(((t * KSTEPS + s) * 64 + lane) << 3)];
                const bf16x8 b = __builtin_bit_cast(bf16x8, bs);
                acc[t] = __builtin_amdgcn_mfma_f32_16x16x32_bf16(a, b, acc[t], 0, 0, 0);
            }
        }

        // epilogue: h = relu(acc + c), dot with w2, reduce over the 16 cols
        float sr[4] = {0.f, 0.f, 0.f, 0.f};
        #pragma unroll
        for (int t = 0; t < NTILES; ++t) {
            const float2 cw = cw_all[t * 16 + m];
            #pragma unroll
            for (int r = 0; r < 4; ++r) {
                float h = acc[t][r] + cw.x;
                h = h > 0.f ? h : 0.f;
                sr[r] += h * cw.y;
            }
        }
        #pragma unroll
        for (int d = 1; d < 16; d <<= 1) {
            #pragma unroll
            for (int r = 0; r < 4; ++r) sr[r] += __shfl_xor(sr[r], d, 64);
        }
        // lanes 0,16,32,48 each store a float4 -> one contiguous 64B segment
        if (m == 0) {
            const int orow = c * 16 + (g << 2);   // C row = g*4 + r
            const float4 v = make_float4(sr[0] + bias2, sr[1] + bias2,
                                         sr[2] + bias2, sr[3] + bias2);
            if (orow + 3 < n) {
                *(float4*)(out + orow) = v;
            } else {
                if (orow     < n) out[orow]     = v.x;
                if (orow + 1 < n) out[orow + 1] = v.y;
                if (orow + 2 < n) out[orow + 2] = v.z;
                if (orow + 3 < n) out[orow + 3] = v.w;
            }
        }

        #pragma unroll
        for (int i = 0; i < 8; ++i) cur[i] = nxt[i];
    }
#undef LOAD_CHUNK
}

extern "C" void kernel_launch(void* const* d_in, const int* in_sizes, int n_in,
                              void* d_out, int out_size, void* d_ws, size_t ws_size,
                              hipStream_t stream) {
    const float* node_hidden = (const float*)d_in[0];
    const float* h_glob      = (const float*)d_in[1];
    const float* state       = (const float*)d_in[2];
    const float* validity    = (const float*)d_in[3];
    const float* W_hl1 = (const float*)d_in[4];  const float* b_hl1 = (const float*)d_in[5];
    const float* W_hl2 = (const float*)d_in[6];  const float* b_hl2 = (const float*)d_in[7];
    const float* W_in1 = (const float*)d_in[8];  const float* b_in1 = (const float*)d_in[9];
    const float* W_in2 = (const float*)d_in[10]; const float* b_in2 = (const float*)d_in[11];
    const float* W_ex1 = (const float*)d_in[12]; const float* b_ex1 = (const float*)d_in[13];
    const float* W_ex2 = (const float*)d_in[14]; const float* b_ex2 = (const float*)d_in[15];
    const float* W_tp1 = (const float*)d_in[16]; const float* b_tp1 = (const float*)d_in[17];
    const float* W_tp2 = (const float*)d_in[18]; const float* b_tp2 = (const float*)d_in[19];

    float* out = (float*)d_out;
    float* ws  = (float*)d_ws;
    const int n = in_sizes[0] / HID;   // 400000

    prep_kernel<<<1, 256, 0, stream>>>(node_hidden, h_glob, state, validity,
                                       W_hl1, b_hl1, W_hl2, b_hl2,
                                       W_in1, b_in1, W_in2, b_in2,
                                       W_ex1, b_ex1, W_ex2, b_ex2,
                                       W_tp1, b_tp1, W_tp2, b_tp2,
                                       out, ws);
    teleport_kernel<<<GRID_BLOCKS, 256, 0, stream>>>(node_hidden, ws, out + 39, n);
}

// Round 4
// 84.776 us; speedup vs baseline: 3.1475x; 3.1475x over previous
//
#include <hip/hip_runtime.h>
#include <hip/hip_bf16.h>
#include <stdint.h>

typedef __attribute__((ext_vector_type(8))) short short8;
typedef __bf16 bf16x8 __attribute__((ext_vector_type(8)));
typedef __attribute__((ext_vector_type(4))) float f32x4;

#define HID 128
#define NTILES 8   // 8 column tiles of 16 -> 128 hidden units
#define KSTEPS 4   // 4 K-steps of 32 -> K=128

// ws layout (float index): [0,8192) bfrag (short[16384]); [8192,8448) cw as float2
// pairs {c[j], w2[j]}; [8448] b2.  LDS copy: 2112 * int4 = 33792 B (floats [0,8448)).
#define WS_CW_F   8192
#define WS_B2_F   8448

#define GRID_BLOCKS 1024
#define WAVES_PER_BLOCK 8

// ---------------- prep: heads (out[0:39], fp32 exact) + pack teleport weights into ws
__global__ void prep_kernel(const float* __restrict__ node_hidden,
                            const float* __restrict__ h_glob,
                            const float* __restrict__ state,
                            const float* __restrict__ validity,
                            const float* __restrict__ W_hl1, const float* __restrict__ b_hl1,
                            const float* __restrict__ W_hl2, const float* __restrict__ b_hl2,
                            const float* __restrict__ W_in1, const float* __restrict__ b_in1,
                            const float* __restrict__ W_in2, const float* __restrict__ b_in2,
                            const float* __restrict__ W_ex1, const float* __restrict__ b_ex1,
                            const float* __restrict__ W_ex2, const float* __restrict__ b_ex2,
                            const float* __restrict__ W_tp1, const float* __restrict__ b_tp1,
                            const float* __restrict__ W_tp2, const float* __restrict__ b_tp2,
                            float* __restrict__ out, float* __restrict__ ws)
{
    __shared__ float feats[264];
    __shared__ float hidden[3 * 128];
    const int tid = threadIdx.x;

    for (int i = tid; i < 264; i += 256) {
        float v;
        if (i < 128)      v = node_hidden[i];       // feats = [cur, h_glob, state]
        else if (i < 256) v = h_glob[i - 128];
        else              v = state[i - 256];
        feats[i] = v;
    }
    __syncthreads();

    for (int hid = tid; hid < 384; hid += 256) {
        const int head = hid >> 7, j = hid & 127;
        const float* W1 = (head == 0) ? W_hl1 : (head == 1 ? W_in1 : W_ex1);
        const float* b1 = (head == 0) ? b_hl1 : (head == 1 ? b_in1 : b_ex1);
        float h = b1[j];
        for (int i = 0; i < 264; ++i) h += feats[i] * W1[i * 128 + j];
        hidden[hid] = h > 0.f ? h : 0.f;
    }
    __syncthreads();

    if (tid < 39) {
        int head, col, od;
        const float *W2, *b2;
        if (tid < 4)      { head = 0; col = tid;     W2 = W_hl2; b2 = b_hl2; od = 4;  }
        else if (tid < 9) { head = 1; col = tid - 4; W2 = W_in2; b2 = b_in2; od = 5;  }
        else              { head = 2; col = tid - 9; W2 = W_ex2; b2 = b_ex2; od = 30; }
        float o = b2[col];
        const float* h = &hidden[head * 128];
        for (int i = 0; i < 128; ++i) o += h[i] * W2[i * od + col];
        if (head == 2) o += logf(validity[col]);
        out[tid] = o;
    }

    // ---- pack B = W_tp1[128:256,:] as bf16 MFMA B-fragments into ws
    short* bfrag = (short*)ws;
    for (int idx = tid; idx < HID * HID; idx += 256) {
        const int k = idx >> 7, nn = idx & 127;
        const int t = nn >> 4, cc = nn & 15;
        const int s = k >> 5, rr = k & 31;
        const int g = rr >> 3, j = rr & 7;
        const int lane = cc + (g << 4);
        bfrag[(((t * KSTEPS + s) * 64 + lane) << 3) + j] =
            (short)__builtin_bit_cast(unsigned short, (__bf16)W_tp1[(128 + k) * HID + nn]);
    }
    // ---- constant layer-1 offset: c = b1 + h_glob @ W1[0:128] + state @ W1[256:264]
    for (int j = tid; j < HID; j += 256) {
        float c = b_tp1[j];
        for (int i = 0; i < 128; ++i) c += h_glob[i] * W_tp1[i * HID + j];
        for (int i = 0; i < 8;  ++i)  c += state[i] * W_tp1[(256 + i) * HID + j];
        ws[WS_CW_F + 2 * j]     = c;
        ws[WS_CW_F + 2 * j + 1] = W_tp2[j];
    }
    if (tid == 0) ws[WS_B2_F] = b_tp2[0];
}

// ---------------- teleport: per-node FFN, bf16 MFMA, fused epilogue -> out[39 + i]
// Loop nest t-outer/s-inner: single f32x4 accumulator reused per tile ->
// live state ~45 VGPR, no spills, TLP (8 waves/SIMD) hides memory latency.
__launch_bounds__(512)
__global__ void teleport_kernel(const float* __restrict__ node_hidden, // n x 128
                                const float* __restrict__ ws,          // packed weights
                                float* __restrict__ out,               // pre-offset (+39)
                                int n)
{
    __shared__ __align__(16) unsigned char smem[33792]; // bfrag 32KB | cw 1KB
    const int tid = threadIdx.x;

    // coalesced ws -> LDS copy (2112 int4)
    {
        const int4* wsv = (const int4*)ws;
        int4* sv = (int4*)smem;
        for (int i = tid; i < 2112; i += 512) sv[i] = wsv[i];
    }
    const float bias2 = ws[WS_B2_F];
    __syncthreads();

    const short*  bfrag  = (const short*)smem;
    const float2* cw_all = (const float2*)(smem + 32768);

    const int lane = tid & 63;
    const int wave = tid >> 6;
    const int m = lane & 15;   // A row within tile / C col (hidden unit)
    const int g = lane >> 4;   // k-group / C row-group

    const int nChunks = (n + 15) >> 4;
    const int gstride = gridDim.x * WAVES_PER_BLOCK;

    for (int c = blockIdx.x * WAVES_PER_BLOCK + wave; c < nChunks; c += gstride) {
        const int row = min(c * 16 + m, n - 1);
        const float4* Ar = (const float4*)(node_hidden + (size_t)row * HID);

        // load + convert this chunk's A fragments: 4 x bf16x8 (16 VGPRs)
        bf16x8 abf[KSTEPS];
        #pragma unroll
        for (int s = 0; s < KSTEPS; ++s) {
            const float4 fa = Ar[s * 8 + g * 2];
            const float4 fb = Ar[s * 8 + g * 2 + 1];
            bf16x8 a;
            a[0] = (__bf16)fa.x; a[1] = (__bf16)fa.y; a[2] = (__bf16)fa.z; a[3] = (__bf16)fa.w;
            a[4] = (__bf16)fb.x; a[5] = (__bf16)fb.y; a[6] = (__bf16)fb.z; a[7] = (__bf16)fb.w;
            abf[s] = a;
        }

        float sr[4] = {0.f, 0.f, 0.f, 0.f};
        #pragma unroll
        for (int t = 0; t < NTILES; ++t) {
            f32x4 acc = (f32x4){0.f, 0.f, 0.f, 0.f};
            #pragma unroll
            for (int s = 0; s < KSTEPS; ++s) {
                const short8 bs = *(const short8*)&bfrag[(((t * KSTEPS + s) * 64 + lane) << 3)];
                const bf16x8 b = __builtin_bit_cast(bf16x8, bs);
                acc = __builtin_amdgcn_mfma_f32_16x16x32_bf16(abf[s], b, acc, 0, 0, 0);
            }
            // fold tile t into the layer-2 partial sums immediately (acc reused)
            const float2 cw = cw_all[t * 16 + m];
            #pragma unroll
            for (int r = 0; r < 4; ++r) {
                float h = acc[r] + cw.x;
                h = h > 0.f ? h : 0.f;
                sr[r] += h * cw.y;
            }
        }

        // reduce over the 16 hidden-cols held across lanes (m dimension)
        #pragma unroll
        for (int d = 1; d < 16; d <<= 1) {
            #pragma unroll
            for (int r = 0; r < 4; ++r) sr[r] += __shfl_xor(sr[r], d, 64);
        }
        // lanes 0,16,32,48 each store one float4 -> contiguous 64B per wave
        if (m == 0) {
            const int orow = c * 16 + (g << 2);   // C row = g*4 + r
            const float4 v = make_float4(sr[0] + bias2, sr[1] + bias2,
                                         sr[2] + bias2, sr[3] + bias2);
            if (orow + 3 < n) {
                *(float4*)(out + orow) = v;
            } else {
                if (orow     < n) out[orow]     = v.x;
                if (orow + 1 < n) out[orow + 1] = v.y;
                if (orow + 2 < n) out[orow + 2] = v.z;
                if (orow + 3 < n) out[orow + 3] = v.w;
            }
        }
    }
}

extern "C" void kernel_launch(void* const* d_in, const int* in_sizes, int n_in,
                              void* d_out, int out_size, void* d_ws, size_t ws_size,
                              hipStream_t stream) {
    const float* node_hidden = (const float*)d_in[0];
    const float* h_glob      = (const float*)d_in[1];
    const float* state       = (const float*)d_in[2];
    const float* validity    = (const float*)d_in[3];
    const float* W_hl1 = (const float*)d_in[4];  const float* b_hl1 = (const float*)d_in[5];
    const float* W_hl2 = (const float*)d_in[6];  const float* b_hl2 = (const float*)d_in[7];
    const float* W_in1 = (const float*)d_in[8];  const float* b_in1 = (const float*)d_in[9];
    const float* W_in2 = (const float*)d_in[10]; const float* b_in2 = (const float*)d_in[11];
    const float* W_ex1 = (const float*)d_in[12]; const float* b_ex1 = (const float*)d_in[13];
    const float* W_ex2 = (const float*)d_in[14]; const float* b_ex2 = (const float*)d_in[15];
    const float* W_tp1 = (const float*)d_in[16]; const float* b_tp1 = (const float*)d_in[17];
    const float* W_tp2 = (const float*)d_in[18]; const float* b_tp2 = (const float*)d_in[19];

    float* out = (float*)d_out;
    float* ws  = (float*)d_ws;
    const int n = in_sizes[0] / HID;   // 400000

    prep_kernel<<<1, 256, 0, stream>>>(node_hidden, h_glob, state, validity,
                                       W_hl1, b_hl1, W_hl2, b_hl2,
                                       W_in1, b_in1, W_in2, b_in2,
                                       W_ex1, b_ex1, W_ex2, b_ex2,
                                       W_tp1, b_tp1, W_tp2, b_tp2,
                                       out, ws);
    teleport_kernel<<<GRID_BLOCKS, 512, 0, stream>>>(node_hidden, ws, out + 39, n);
}